// Round 3
// baseline (287.191 us; speedup 1.0000x reference)
//
#include <hip/hip_runtime.h>

typedef short v8s __attribute__((ext_vector_type(8)));
typedef float v4f __attribute__((ext_vector_type(4)));

#define BM 128
#define BN 128
#define BK 32

__device__ __forceinline__ unsigned short f2bf(float f) {
    unsigned u = __float_as_uint(f);
    unsigned r = u + 0x7fffu + ((u >> 16) & 1u);   // round-to-nearest-even
    return (unsigned short)(r >> 16);
}

__device__ __forceinline__ float bf2f(unsigned short h) {
    return __uint_as_float(((unsigned)h) << 16);
}

__device__ __forceinline__ void async16(const unsigned short* g, unsigned short* l) {
    __builtin_amdgcn_global_load_lds(
        (const __attribute__((address_space(1))) unsigned int*)g,
        (__attribute__((address_space(3))) unsigned int*)l,
        16, 0, 0);
}

// ------------------------------------------- cast F -> bf16 (+ fused zero of accums)
__global__ void cast_f32_bf16(const float* __restrict__ in,
                              unsigned short* __restrict__ out, int n4,
                              float* __restrict__ zbuf, int nzero) {
    int i = blockIdx.x * blockDim.x + threadIdx.x;
    if (i < nzero) zbuf[i] = 0.0f;
    if (i < n4) {
        float4 v = ((const float4*)in)[i];
        ushort4 o;
        o.x = f2bf(v.x); o.y = f2bf(v.y); o.z = f2bf(v.z); o.w = f2bf(v.w);
        ((ushort4*)out)[i] = o;
    }
}

// ------------------------------------------------- transpose + cast P -> Pt bf16
__global__ void transpose_cast(const float* __restrict__ P,
                               unsigned short* __restrict__ Pt, int n) {
    __shared__ unsigned short tile[32][33];
    int bx = blockIdx.x, by = blockIdx.y;
    int tx = threadIdx.x, ty = threadIdx.y;        // 32 x 8
#pragma unroll
    for (int i = 0; i < 4; i++) {
        int k = bx * 32 + ty + i * 8;
        tile[ty + i * 8][tx] = f2bf(P[(size_t)k * n + by * 32 + tx]);
    }
    __syncthreads();
#pragma unroll
    for (int i = 0; i < 4; i++) {
        int nn = by * 32 + ty + i * 8;
        Pt[(size_t)nn * n + bx * 32 + tx] = tile[tx][ty + i * 8];
    }
}

// ----------------------------------------------------------------- GEMM1: Z = A*Bt^T
// Double-buffered LDS pipeline: prefetch tile k+1 after the barrier, compute
// tile k — the prefetch stays in flight across the whole compute phase.
__global__ void gemm1(const unsigned short* __restrict__ A,
                      const unsigned short* __restrict__ Bt,
                      int M, int N, int K,
                      unsigned short* __restrict__ Zb,
                      float* __restrict__ sqn) {
    __shared__ __align__(16) unsigned short As[2][BM * BK];
    __shared__ __align__(16) unsigned short Bs[2][BN * BK];

    const int tid  = threadIdx.x;
    const int lane = tid & 63;
    const int w    = tid >> 6;
    const int wr   = w >> 1;
    const int wc   = w & 1;
    const int quad = lane >> 4;
    const int l15  = lane & 15;

    const long rowA0 = (long)blockIdx.y * BM;
    const long rowB0 = (long)blockIdx.x * BN;

    const int srow  = lane >> 2;
    const int slotg = (lane & 3) ^ ((srow >> 1) & 3);   // XOR-swizzled 16B slot
    const int scol  = slotg * 8;
    const int c0 = w, c1 = w + 4;
    const int ksw = (l15 >> 1) & 3;                     // read-side XOR key

    const unsigned short* gA0 = A  + (rowA0 + c0 * 16 + srow) * (long)K + scol;
    const unsigned short* gA1 = A  + (rowA0 + c1 * 16 + srow) * (long)K + scol;
    const unsigned short* gB0 = Bt + (rowB0 + c0 * 16 + srow) * (long)K + scol;
    const unsigned short* gB1 = Bt + (rowB0 + c1 * 16 + srow) * (long)K + scol;

    auto stage = [&](int buf, int k0) {
        async16(gA0 + k0, &As[buf][c0 * 512]);
        async16(gA1 + k0, &As[buf][c1 * 512]);
        async16(gB0 + k0, &Bs[buf][c0 * 512]);
        async16(gB1 + k0, &Bs[buf][c1 * 512]);
    };

    v4f acc[4][4] = {};
    stage(0, 0);
    int cur = 0;
    for (int k0 = 0; k0 < K; k0 += BK) {
        __syncthreads();                      // drains loads for buf `cur`
        if (k0 + BK < K) stage(cur ^ 1, k0 + BK);

        v8s a[4], b[4];
#pragma unroll
        for (int f = 0; f < 4; ++f)
            a[f] = *(const v8s*)&As[cur][(wr * 64 + f * 16 + l15) * BK + (quad ^ ksw) * 8];
#pragma unroll
        for (int f = 0; f < 4; ++f)
            b[f] = *(const v8s*)&Bs[cur][(wc * 64 + f * 16 + l15) * BK + (quad ^ ksw) * 8];
#pragma unroll
        for (int i = 0; i < 4; ++i)
#pragma unroll
            for (int j = 0; j < 4; ++j)
                acc[i][j] = __builtin_amdgcn_mfma_f32_16x16x32_bf16(a[i], b[j], acc[i][j], 0, 0, 0);
        cur ^= 1;
    }

#pragma unroll
    for (int i = 0; i < 4; ++i) {
        int row0 = (int)rowA0 + wr * 64 + i * 16 + quad * 4;
        float rs[4] = {0.f, 0.f, 0.f, 0.f};
#pragma unroll
        for (int j = 0; j < 4; ++j) {
            int col = (int)rowB0 + wc * 64 + j * 16 + l15;
#pragma unroll
            for (int r = 0; r < 4; ++r) {
                unsigned short b = f2bf(acc[i][j][r]);
                float vb = bf2f(b);
                Zb[(long)(row0 + r) * N + col] = b;
                rs[r] += vb * vb;
            }
        }
#pragma unroll
        for (int r = 0; r < 4; ++r) {
            float s = rs[r];
            s += __shfl_xor(s, 1, 64);
            s += __shfl_xor(s, 2, 64);
            s += __shfl_xor(s, 4, 64);
            s += __shfl_xor(s, 8, 64);
            if (l15 == 0) atomicAdd(&sqn[row0 + r], s);
        }
    }
}

// ------------------------------------------ GEMM2 (symmetric): A = adj(Z*Z^T)
// Upper-triangle blocks, double-buffered LDS, fused degree row-sums.
__global__ void gemm2_sym(const unsigned short* __restrict__ Z,
                          int N, int K,
                          const float* __restrict__ sqn,
                          float* __restrict__ Aout,
                          float* __restrict__ deg) {
    __shared__ __align__(16) unsigned short As[2][BM * BK];
    __shared__ __align__(16) unsigned short Bs[2][BN * BK];

    const int nb = N / BN;
    int rem = blockIdx.x, bi = 0;
    while (rem >= nb - bi) { rem -= nb - bi; ++bi; }
    const int bj = bi + rem;
    const bool diag = (bi == bj);

    const int tid  = threadIdx.x;
    const int lane = tid & 63;
    const int w    = tid >> 6;
    const int wr   = w >> 1;
    const int wc   = w & 1;
    const int quad = lane >> 4;
    const int l15  = lane & 15;

    const long rowA0 = (long)bi * BM;
    const long rowB0 = (long)bj * BN;

    const int srow  = lane >> 2;
    const int slotg = (lane & 3) ^ ((srow >> 1) & 3);
    const int scol  = slotg * 8;
    const int c0 = w, c1 = w + 4;
    const int ksw = (l15 >> 1) & 3;

    const unsigned short* gA0 = Z + (rowA0 + c0 * 16 + srow) * (long)K + scol;
    const unsigned short* gA1 = Z + (rowA0 + c1 * 16 + srow) * (long)K + scol;
    const unsigned short* gB0 = Z + (rowB0 + c0 * 16 + srow) * (long)K + scol;
    const unsigned short* gB1 = Z + (rowB0 + c1 * 16 + srow) * (long)K + scol;

    auto stage = [&](int buf, int k0) {
        async16(gA0 + k0, &As[buf][c0 * 512]);
        async16(gA1 + k0, &As[buf][c1 * 512]);
        async16(gB0 + k0, &Bs[buf][c0 * 512]);
        async16(gB1 + k0, &Bs[buf][c1 * 512]);
    };

    v4f acc[4][4] = {};
    stage(0, 0);
    int cur = 0;
    for (int k0 = 0; k0 < K; k0 += BK) {
        __syncthreads();
        if (k0 + BK < K) stage(cur ^ 1, k0 + BK);

        v8s a[4], b[4];
#pragma unroll
        for (int f = 0; f < 4; ++f)
            a[f] = *(const v8s*)&As[cur][(wr * 64 + f * 16 + l15) * BK + (quad ^ ksw) * 8];
#pragma unroll
        for (int f = 0; f < 4; ++f)
            b[f] = *(const v8s*)&Bs[cur][(wc * 64 + f * 16 + l15) * BK + (quad ^ ksw) * 8];
#pragma unroll
        for (int i = 0; i < 4; ++i)
#pragma unroll
            for (int j = 0; j < 4; ++j)
                acc[i][j] = __builtin_amdgcn_mfma_f32_16x16x32_bf16(a[i], b[j], acc[i][j], 0, 0, 0);
        cur ^= 1;
    }

    float cs[4] = {0.f, 0.f, 0.f, 0.f};
#pragma unroll
    for (int i = 0; i < 4; ++i) {
        int row0 = (int)rowA0 + wr * 64 + i * 16 + quad * 4;
        float rs[4] = {0.f, 0.f, 0.f, 0.f};
#pragma unroll
        for (int j = 0; j < 4; ++j) {
            int col = (int)rowB0 + wc * 64 + j * 16 + l15;
            float sc = sqn[col];
            float vals[4];
#pragma unroll
            for (int r = 0; r < 4; ++r) {
                int row = row0 + r;
                float v;
                if (diag && row == col) {
                    v = 1.0f;
                } else {
                    float sq = sqn[row] + sc - 2.0f * acc[i][j][r];
                    v = __expf(-__fsqrt_rn(fmaxf(sq, 0.0f)));
                }
                vals[r] = v;
                rs[r] += v;
                cs[j] += v;
            }
#pragma unroll
            for (int r = 0; r < 4; ++r)
                Aout[(long)(row0 + r) * N + col] = vals[r];
            if (!diag) {     // transposed tile: 4 consecutive rows -> float4
                float4 t = make_float4(vals[0], vals[1], vals[2], vals[3]);
                *(float4*)&Aout[(long)col * N + row0] = t;
            }
        }
#pragma unroll
        for (int r = 0; r < 4; ++r) {
            float s = rs[r];
            s += __shfl_xor(s, 1, 64);
            s += __shfl_xor(s, 2, 64);
            s += __shfl_xor(s, 4, 64);
            s += __shfl_xor(s, 8, 64);
            if (l15 == 0) atomicAdd(&deg[row0 + r], s);
        }
    }
    if (!diag) {
#pragma unroll
        for (int j = 0; j < 4; ++j) {
            float s = cs[j];
            s += __shfl_xor(s, 16, 64);
            s += __shfl_xor(s, 32, 64);
            if (quad == 0) {
                int col = (int)rowB0 + wc * 64 + j * 16 + l15;
                atomicAdd(&deg[col], s);
            }
        }
    }
}

// ------------------- normalized = rsqrt(deg_i) * A_ij * rsqrt(deg_j) (inline)
__global__ void normalize_k(const float* __restrict__ Amat,
                            const float* __restrict__ deg,
                            float* __restrict__ outN) {
    size_t i4 = (size_t)blockIdx.x * blockDim.x + threadIdx.x;
    size_t idx = i4 * 4;
    int row = (int)(idx >> 12);        // N = 4096
    int col = (int)(idx & 4095);
    float di = rsqrtf(deg[row]);
    float4 a  = ((const float4*)Amat)[i4];
    float4 d4 = ((const float4*)deg)[col >> 2];
    float4 o;
    o.x = di * a.x * rsqrtf(d4.x);
    o.y = di * a.y * rsqrtf(d4.y);
    o.z = di * a.z * rsqrtf(d4.z);
    o.w = di * a.w * rsqrtf(d4.w);
    ((float4*)outN)[i4] = o;
}

extern "C" void kernel_launch(void* const* d_in, const int* in_sizes, int n_in,
                              void* d_out, int out_size, void* d_ws, size_t ws_size,
                              hipStream_t stream) {
    const int BS_ = 4096, D_ = 2048, R_ = 2048;
    const float* F = (const float*)d_in[0];
    const float* P = (const float*)d_in[1];

    float* outN = (float*)d_out;                      // normalized  [BS x BS]
    float* outA = outN + (size_t)BS_ * BS_;           // adjacency   [BS x BS]

    char* ws = (char*)d_ws;
    unsigned short* Fb  = (unsigned short*)ws;                                   // 16 MB
    unsigned short* Ptb = (unsigned short*)(ws + (size_t)BS_ * D_ * 2);          //  8 MB
    unsigned short* Zb  = (unsigned short*)(ws + (size_t)BS_ * D_ * 2
                                               + (size_t)D_ * R_ * 2);           // 16 MB
    float* sqn  = (float*)(ws + (size_t)BS_ * D_ * 2 + (size_t)D_ * R_ * 2
                              + (size_t)BS_ * R_ * 2);
    float* deg  = sqn + BS_;

    // 1. cast F -> bf16 (+ zero sqn/deg)
    cast_f32_bf16<<<(BS_ * D_ / 4 + 255) / 256, 256, 0, stream>>>(
        F, Fb, BS_ * D_ / 4, sqn, 2 * BS_);
    transpose_cast<<<dim3(D_ / 32, R_ / 32), dim3(32, 8), 0, stream>>>(P, Ptb, D_);

    // 2. Z = F * P (bf16 out) + fused row sq-norms
    gemm1<<<dim3(R_ / 128, BS_ / 128), 256, 0, stream>>>(
        Fb, Ptb, BS_, R_, D_, Zb, sqn);

    // 3. adjacency from Z*Z^T, upper-triangle blocks, fused degree sums
    const int nb = BS_ / 128;
    gemm2_sym<<<nb * (nb + 1) / 2, 256, 0, stream>>>(Zb, BS_, R_, sqn, outA, deg);

    // 4. normalized output (inline rsqrt of deg)
    normalize_k<<<(BS_ * (size_t)BS_ / 4 + 255) / 256, 256, 0, stream>>>(
        outA, deg, outN);
}